// Round 1
// baseline (6415.034 us; speedup 1.0000x reference)
//
#include <hip/hip_runtime.h>

#define L_IMG 12
#define BATCH 64
#define NCLS  1000
#define NT    8
#define MTXT  12
#define DIM   512
#define NTM   96            // MTXT*NT rows of text tokens per class
#define SCALEF 0.044194173824159216f   // 1/sqrt(512)

// ---------- bf16 helpers (OCP bf16 as raw ushort) ----------
__device__ __forceinline__ float bf2f(unsigned short u) {
    return __uint_as_float(((unsigned int)u) << 16);
}
__device__ __forceinline__ unsigned short f2bf(float f) {
    unsigned int u = __float_as_uint(f);
    u += 0x7FFFu + ((u >> 16) & 1u);   // round-to-nearest-even
    return (unsigned short)(u >> 16);
}
__device__ __forceinline__ float4 load4f(const float* p) { return *(const float4*)p; }
__device__ __forceinline__ float4 load4f(const unsigned short* p) {
    ushort4 u = *(const ushort4*)p;
    return make_float4(bf2f(u.x), bf2f(u.y), bf2f(u.z), bf2f(u.w));
}
__device__ __forceinline__ void storeo(float* p, float v) { *p = v; }
__device__ __forceinline__ void storeo(unsigned short* p, float v) { *p = f2bf(v); }

// ---------- generic tiled GEMM: C[M,N] = A[M,K] @ W[N,K]^T (+bias)(*scale) ----------
// Optional: padded-row zeroing (rows with (row & pad_mask) >= pad_valid are treated
// as zero in and out), and sum-of-squares accumulation into n2[(m0>>10)*512 + n].
#define BKT 32
#define LDT 68   // 68*4B stride: keeps float4 LDS reads 16B-aligned, conflicts <=4-way

template<typename InT, typename OutT>
__global__ __launch_bounds__(256)
void gemm_bt(const InT* __restrict__ A, const float* __restrict__ W,
             const float* __restrict__ bias, OutT* __restrict__ Co,
             float* __restrict__ n2, int M, int N, int K,
             float out_scale, int pad_mask, int pad_valid)
{
    __shared__ float As[BKT * LDT];
    __shared__ float Ws[BKT * LDT];
    __shared__ float sq[64];
    const int tid = threadIdx.x;
    const int m0 = blockIdx.y << 6, n0 = blockIdx.x << 6;
    const int tx = tid & 15, ty = tid >> 4;
    float acc[4][4] = {};

    for (int k0 = 0; k0 < K; k0 += BKT) {
        #pragma unroll
        for (int i = 0; i < 2; i++) {
            int slot = tid + (i << 8);            // 512 float4 slots: 64 rows x 8
            int r = slot >> 3, kq = slot & 7;
            int mr = m0 + r;
            float4 v = make_float4(0.f, 0.f, 0.f, 0.f);
            if (!pad_mask || ((mr & pad_mask) < pad_valid))
                v = load4f(A + (size_t)mr * K + k0 + (kq << 2));
            As[(kq*4+0)*LDT + r] = v.x;
            As[(kq*4+1)*LDT + r] = v.y;
            As[(kq*4+2)*LDT + r] = v.z;
            As[(kq*4+3)*LDT + r] = v.w;
            float4 w = *(const float4*)(W + (size_t)(n0 + r) * K + k0 + (kq << 2));
            Ws[(kq*4+0)*LDT + r] = w.x;
            Ws[(kq*4+1)*LDT + r] = w.y;
            Ws[(kq*4+2)*LDT + r] = w.z;
            Ws[(kq*4+3)*LDT + r] = w.w;
        }
        __syncthreads();
        #pragma unroll
        for (int kk = 0; kk < BKT; kk++) {
            float4 a = *(const float4*)(As + kk*LDT + ty*4);
            float4 w = *(const float4*)(Ws + kk*LDT + tx*4);
            acc[0][0] += a.x*w.x; acc[0][1] += a.x*w.y; acc[0][2] += a.x*w.z; acc[0][3] += a.x*w.w;
            acc[1][0] += a.y*w.x; acc[1][1] += a.y*w.y; acc[1][2] += a.y*w.z; acc[1][3] += a.y*w.w;
            acc[2][0] += a.z*w.x; acc[2][1] += a.z*w.y; acc[2][2] += a.z*w.z; acc[2][3] += a.z*w.w;
            acc[3][0] += a.w*w.x; acc[3][1] += a.w*w.y; acc[3][2] += a.w*w.z; acc[3][3] += a.w*w.w;
        }
        __syncthreads();
    }

    const bool do_sq = (n2 != nullptr);
    if (do_sq) { if (tid < 64) sq[tid] = 0.f; __syncthreads(); }
    float colsq[4] = {0.f, 0.f, 0.f, 0.f};
    #pragma unroll
    for (int i = 0; i < 4; i++) {
        int mr = m0 + ty*4 + i;
        bool valid = !pad_mask || ((mr & pad_mask) < pad_valid);
        #pragma unroll
        for (int j = 0; j < 4; j++) {
            int n = n0 + tx*4 + j;
            float v = acc[i][j];
            if (bias) v += bias[n];
            v *= out_scale;
            if (!valid) v = 0.f;
            storeo(Co + (size_t)mr * N + n, v);
            colsq[j] += v * v;
        }
    }
    if (do_sq) {
        #pragma unroll
        for (int j = 0; j < 4; j++) atomicAdd(&sq[tx*4+j], colsq[j]);
        __syncthreads();
        if (tid < 64) atomicAdd(&n2[(m0 >> 10) * DIM + n0 + tid], sq[tid]);
    }
}

// ---------- self-attention over the 12-layer axis, one block per batch ----------
__global__ __launch_bounds__(256)
void attn_kernel(const float* __restrict__ qkv, float* __restrict__ ao)
{
    __shared__ float lq[L_IMG * DIM];
    __shared__ float lk[L_IMG * DIM];
    __shared__ float sc[L_IMG * L_IMG];
    __shared__ float sa[L_IMG * L_IMG];
    const int b = blockIdx.x, tid = threadIdx.x;

    for (int i = 0; i < 6; i++) {
        int slot = tid + (i << 8);             // 1536 slots = 12 rows * 128 f4
        int l = slot >> 7, e4 = slot & 127;
        const float* row = qkv + (size_t)(l * BATCH + b) * 1536;
        *(float4*)(lq + l*DIM + e4*4) = *(const float4*)(row + e4*4);
        *(float4*)(lk + l*DIM + e4*4) = *(const float4*)(row + DIM + e4*4);
    }
    __syncthreads();
    if (tid < 144) {
        int l = tid / 12, m = tid % 12;
        float a = 0.f;
        for (int d4 = 0; d4 < 128; d4++) {
            float4 q = *(const float4*)(lq + l*DIM + d4*4);
            float4 k = *(const float4*)(lk + m*DIM + d4*4);
            a += q.x*k.x + q.y*k.y + q.z*k.z + q.w*k.w;
        }
        sc[tid] = a * SCALEF;
    }
    __syncthreads();
    if (tid < 12) {
        float mx = -1e30f;
        for (int m = 0; m < 12; m++) mx = fmaxf(mx, sc[tid*12 + m]);
        float e[12], s = 0.f;
        for (int m = 0; m < 12; m++) { e[m] = __expf(sc[tid*12 + m] - mx); s += e[m]; }
        float inv = 1.f / s;
        for (int m = 0; m < 12; m++) sa[tid*12 + m] = e[m] * inv;
    }
    __syncthreads();
    for (int i = 0; i < 2; i++) {
        int e = tid + (i << 8);
        float vv[12];
        #pragma unroll
        for (int m = 0; m < 12; m++)
            vv[m] = qkv[(size_t)(m * BATCH + b) * 1536 + 1024 + e];
        #pragma unroll
        for (int l = 0; l < 12; l++) {
            float a = 0.f;
            #pragma unroll
            for (int m = 0; m < 12; m++) a += sa[l*12 + m] * vv[m];
            ao[(size_t)(l * BATCH + b) * DIM + e] = a;
        }
    }
}

// ---------- normalize image features (xs layer 11), one block per batch ----------
__global__ __launch_bounds__(256)
void img_kernel(const float* __restrict__ xs, float* __restrict__ imgn)
{
    __shared__ float red[256];
    const int b = blockIdx.x, tid = threadIdx.x;
    const float* row = xs + (size_t)(11 * BATCH + b) * DIM;
    float v0 = row[tid], v1 = row[tid + 256];
    red[tid] = v0*v0 + v1*v1;
    __syncthreads();
    for (int s = 128; s > 0; s >>= 1) {
        if (tid < s) red[tid] += red[tid + s];
        __syncthreads();
    }
    float inv = rsqrtf(red[0]);
    imgn[b*DIM + tid]       = v0 * inv;
    imgn[b*DIM + tid + 256] = v1 * inv;
}

// ---------- fused cross-attention: scores + softmax(m) + sum_l + ctx, block=(b,c) ----------
__global__ __launch_bounds__(256)
void cross_kernel(const float* __restrict__ q2s, const unsigned short* __restrict__ k2,
                  const unsigned short* __restrict__ v2, unsigned short* __restrict__ ctx)
{
    __shared__ float lq[L_IMG * DIM];          // 24 KB (q2 pre-scaled)
    __shared__ unsigned int lk[32 * 257];      // 32 rows x 256 uints (+1 pad) = 32.9 KB
    __shared__ float sc[L_IMG * NTM];          // 4.6 KB raw scores [l][tm]
    __shared__ float wf[NTM];
    const int b = blockIdx.x, c = blockIdx.y, tid = threadIdx.x;

    for (int i = 0; i < 6; i++) {
        int slot = tid + (i << 8);
        int l = slot >> 7, e4 = slot & 127;
        *(float4*)(lq + l*DIM + e4*4) =
            *(const float4*)(q2s + (size_t)(l * BATCH + b) * DIM + e4*4);
    }
    const size_t kbase = (size_t)c * NTM * DIM;

    for (int ch = 0; ch < 3; ch++) {
        __syncthreads();
        const unsigned int* ksrc = (const unsigned int*)(k2 + kbase + (size_t)ch * 32 * DIM);
        for (int i = 0; i < 32; i++) {
            int slot = tid + (i << 8);          // 8192 uints: 32 rows x 256
            int r = slot >> 8, d2 = slot & 255;
            lk[r*257 + d2] = ksrc[r*256 + d2];
        }
        __syncthreads();
        for (int j = 0; j < 2; j++) {
            int p = tid + (j << 8);
            if (p < 384) {                      // 12 l x 32 tm rows this chunk
                int l = p >> 5, tmi = p & 31;
                const unsigned int* kr = lk + tmi*257;
                const float2* qr = (const float2*)(lq + l*DIM);
                float a = 0.f;
                #pragma unroll 8
                for (int d2 = 0; d2 < 256; d2++) {
                    unsigned int kw = kr[d2];
                    float2 q = qr[d2];
                    a += q.x * __uint_as_float(kw << 16);
                    a += q.y * __uint_as_float(kw & 0xFFFF0000u);
                }
                sc[l*NTM + (ch << 5) + tmi] = a;
            }
        }
    }
    __syncthreads();
    // softmax over m (stride 8 in tm = m*8 + t), per (t,l)
    if (tid < NTM) {
        int t = tid & 7, l = tid >> 3;
        float mx = -1e30f;
        for (int m = 0; m < 12; m++) mx = fmaxf(mx, sc[l*NTM + (m << 3) + t]);
        float e[12], s = 0.f;
        for (int m = 0; m < 12; m++) { e[m] = __expf(sc[l*NTM + (m << 3) + t] - mx); s += e[m]; }
        float inv = 1.f / s;
        for (int m = 0; m < 12; m++) sc[l*NTM + (m << 3) + t] = e[m] * inv;
    }
    __syncthreads();
    if (tid < NTM) {               // w[tm] = sum_l a2 / 96
        float s = 0.f;
        for (int l = 0; l < 12; l++) s += sc[l*NTM + tid];
        wf[tid] = s * (1.f / 96.f);
    }
    __syncthreads();
    const unsigned short* vbase = v2 + kbase;
    float acc0 = 0.f, acc1 = 0.f;
    #pragma unroll 8
    for (int tm = 0; tm < NTM; tm++) {
        float w = wf[tm];
        acc0 += w * bf2f(vbase[(size_t)tm * DIM + tid]);
        acc1 += w * bf2f(vbase[(size_t)tm * DIM + tid + 256]);
    }
    size_t obase = ((size_t)((b << 10) + c)) * DIM;   // ctx padded to 1024 classes/b
    ctx[obase + tid]       = f2bf(acc0);
    ctx[obase + tid + 256] = f2bf(acc1);
}

// ---------- u[b,d] = exp(ls) * img_n[b,d] / ||txt[b,:,d]|| ----------
__global__ __launch_bounds__(256)
void u_kernel(const float* __restrict__ imgn, const float* __restrict__ n2,
              const float* __restrict__ logit_scale, float* __restrict__ u)
{
    int i = blockIdx.x * 256 + threadIdx.x;   // 64*512
    float els = expf(logit_scale[0]);
    u[i] = els * imgn[i] * rsqrtf(n2[i]);
}

// ---------- logits[b,c] = sum_d u[b,d] * txt[b,c,d]; one wave per c ----------
__global__ __launch_bounds__(256)
void logits_kernel(const unsigned short* __restrict__ txt, const float* __restrict__ u,
                   float* __restrict__ out)
{
    __shared__ float lu[DIM];
    const int b = blockIdx.y, cg = blockIdx.x, tid = threadIdx.x;
    lu[tid]       = u[b*DIM + tid];
    lu[tid + 256] = u[b*DIM + tid + 256];
    __syncthreads();
    int wave = tid >> 6, lane = tid & 63;
    int c = (cg << 2) + wave;
    const unsigned short* row = txt + ((size_t)((b << 10) + c)) * DIM;
    ushort4 p0 = ((const ushort4*)row)[lane*2];
    ushort4 p1 = ((const ushort4*)row)[lane*2 + 1];
    int d0 = lane * 8;
    float s = bf2f(p0.x)*lu[d0]   + bf2f(p0.y)*lu[d0+1] + bf2f(p0.z)*lu[d0+2] + bf2f(p0.w)*lu[d0+3]
            + bf2f(p1.x)*lu[d0+4] + bf2f(p1.y)*lu[d0+5] + bf2f(p1.z)*lu[d0+6] + bf2f(p1.w)*lu[d0+7];
    #pragma unroll
    for (int off = 32; off > 0; off >>= 1) s += __shfl_down(s, off, 64);
    if (lane == 0) out[b*NCLS + c] = s;
}

extern "C" void kernel_launch(void* const* d_in, const int* in_sizes, int n_in,
                              void* d_out, int out_size, void* d_ws, size_t ws_size,
                              hipStream_t stream)
{
    const float* x   = (const float*)d_in[0];   // [12,64,512]
    const float* tfe = (const float*)d_in[1];   // [1000,12,8,512]
    const float* siw = (const float*)d_in[2];   // [1536,512]
    const float* sib = (const float*)d_in[3];
    const float* sow = (const float*)d_in[4];   // [512,512]
    const float* sob = (const float*)d_in[5];
    const float* ciw = (const float*)d_in[6];   // [1536,512]
    const float* cib = (const float*)d_in[7];
    const float* cow = (const float*)d_in[8];   // [512,512]
    const float* cob = (const float*)d_in[9];
    const float* ls  = (const float*)d_in[10];
    float* out = (float*)d_out;

    char* w = (char*)d_ws;
    float* qkv = (float*)w;                   w += 768 * 1536 * 4;      // 4.7 MB
    float* ao  = (float*)w;                   w += 768 * 512 * 4;
    float* xs  = (float*)w;                   w += 768 * 512 * 4;
    float* q2s = (float*)w;                   w += 768 * 512 * 4;
    unsigned short* k2  = (unsigned short*)w; w += (size_t)96000 * 512 * 2;  // 98.3 MB
    unsigned short* v2  = (unsigned short*)w; w += (size_t)96000 * 512 * 2;  // 98.3 MB
    unsigned short* ctx = (unsigned short*)w; w += (size_t)65536 * 512 * 2;  // 67.1 MB (padded 1024/b)
    unsigned short* txt = (unsigned short*)w; w += (size_t)65536 * 512 * 2;  // 67.1 MB
    float* n2   = (float*)w;                  w += 64 * 512 * 4;
    float* uu   = (float*)w;                  w += 64 * 512 * 4;
    float* imgn = (float*)w;                  w += 64 * 512 * 4;
    // total ws use ~341 MB

    hipMemsetAsync(n2, 0, 64 * 512 * 4, stream);

    // self-attn: qkv proj -> attention -> out proj -> image-feature norm -> q2 proj (pre-scaled)
    gemm_bt<float, float><<<dim3(24, 12), 256, 0, stream>>>(
        x, siw, sib, qkv, nullptr, 768, 1536, 512, 1.f, 0, 0);
    attn_kernel<<<64, 256, 0, stream>>>(qkv, ao);
    gemm_bt<float, float><<<dim3(8, 12), 256, 0, stream>>>(
        ao, sow, sob, xs, nullptr, 768, 512, 512, 1.f, 0, 0);
    img_kernel<<<64, 256, 0, stream>>>(xs, imgn);
    gemm_bt<float, float><<<dim3(8, 12), 256, 0, stream>>>(
        xs, ciw, cib, q2s, nullptr, 768, 512, 512, SCALEF, 0, 0);

    // k2/v2 projections of text features (bf16 out)
    gemm_bt<float, unsigned short><<<dim3(8, 1500), 256, 0, stream>>>(
        tfe, ciw + 512*512, cib + 512, k2, nullptr, 96000, 512, 512, 1.f, 0, 0);
    gemm_bt<float, unsigned short><<<dim3(8, 1500), 256, 0, stream>>>(
        tfe, ciw + 1024*512, cib + 1024, v2, nullptr, 96000, 512, 512, 1.f, 0, 0);

    // fused cross attention -> ctx[b, c(pad1024), d]
    cross_kernel<<<dim3(64, 1000), 256, 0, stream>>>(q2s, k2, v2, ctx);

    // txt = ctx @ cow^T + cob, with sum-of-squares over c into n2[b,d]
    gemm_bt<unsigned short, unsigned short><<<dim3(8, 1024), 256, 0, stream>>>(
        ctx, cow, cob, txt, n2, 65536, 512, 512, 1.f, 1023, 1000);

    u_kernel<<<128, 256, 0, stream>>>(imgn, n2, ls, uu);
    logits_kernel<<<dim3(250, 64), 256, 0, stream>>>(txt, uu, out);
}

// Round 2
// 1485.664 us; speedup vs baseline: 4.3180x; 4.3180x over previous
//
#include <hip/hip_runtime.h>

#define L_IMG 12
#define BATCH 64
#define NCLS  1000
#define DIM   512
#define NTM   96
#define SCALEF 0.044194173824159216f   // 1/sqrt(512)

typedef __attribute__((ext_vector_type(8))) short bf16x8;
typedef __attribute__((ext_vector_type(4))) float f32x4;

// ---------- bf16 helpers ----------
__device__ __forceinline__ float bf2f(unsigned short u) {
    return __uint_as_float(((unsigned int)u) << 16);
}
__device__ __forceinline__ unsigned short f2bf(float f) {
    unsigned int u = __float_as_uint(f);
    u += 0x7FFFu + ((u >> 16) & 1u);
    return (unsigned short)(u >> 16);
}
__device__ __forceinline__ void storeo(float* p, float v) { *p = v; }
__device__ __forceinline__ void storeo(unsigned short* p, float v) { *p = f2bf(v); }

// ---------- fp32 -> bf16 convert (n multiple of 4) ----------
__global__ __launch_bounds__(256)
void f2bf_kernel(const float* __restrict__ in, unsigned short* __restrict__ out, int n)
{
    int i = (blockIdx.x * 256 + threadIdx.x) * 4;
    if (i < n) {
        float4 v = *(const float4*)(in + i);
        ushort4 o;
        o.x = f2bf(v.x); o.y = f2bf(v.y); o.z = f2bf(v.z); o.w = f2bf(v.w);
        *(ushort4*)(out + i) = o;
    }
}

// ---------- Wvo[d,k] = sum_e cow[d,e]*cWv[e,k] (bf16 out), bvo[d] = sum_e cow[d,e]*cbv[e] ----------
__global__ __launch_bounds__(256)
void fold_wvo(const float* __restrict__ cow, const float* __restrict__ cWv,
              const float* __restrict__ cbv, unsigned short* __restrict__ Wvob,
              float* __restrict__ bvo)
{
    __shared__ float crow[DIM];
    __shared__ float red[256];
    const int d = blockIdx.x, t = threadIdx.x;
    float c0 = cow[d * DIM + t], c1 = cow[d * DIM + t + 256];
    crow[t] = c0; crow[t + 256] = c1;
    red[t] = c0 * cbv[t] + c1 * cbv[t + 256];
    __syncthreads();
    for (int s = 128; s > 0; s >>= 1) {
        if (t < s) red[t] += red[t + s];
        __syncthreads();
    }
    if (t == 0) bvo[d] = red[0];
    float a0 = 0.f, a1 = 0.f;
    for (int e = 0; e < DIM; e++) {
        float ce = crow[e];
        a0 += ce * cWv[e * DIM + t];
        a1 += ce * cWv[e * DIM + t + 256];
    }
    Wvob[d * DIM + t]       = f2bf(a0);
    Wvob[d * DIM + t + 256] = f2bf(a1);
}

// ---------- small fp32 tiled GEMM: C[M,N] = (A[M,K] @ W[N,K]^T + bias) * scale ----------
#define BKT 32
#define LDT 68
__global__ __launch_bounds__(256)
void gemm_bt_f32(const float* __restrict__ A, const float* __restrict__ W,
                 const float* __restrict__ bias, float* __restrict__ Co,
                 int M, int N, int K, float out_scale)
{
    __shared__ float As[BKT * LDT];
    __shared__ float Ws[BKT * LDT];
    const int tid = threadIdx.x;
    const int m0 = blockIdx.y << 6, n0 = blockIdx.x << 6;
    const int tx = tid & 15, ty = tid >> 4;
    float acc[4][4] = {};
    for (int k0 = 0; k0 < K; k0 += BKT) {
        #pragma unroll
        for (int i = 0; i < 2; i++) {
            int slot = tid + (i << 8);
            int r = slot >> 3, kq = slot & 7;
            float4 v = *(const float4*)(A + (size_t)(m0 + r) * K + k0 + (kq << 2));
            As[(kq*4+0)*LDT + r] = v.x; As[(kq*4+1)*LDT + r] = v.y;
            As[(kq*4+2)*LDT + r] = v.z; As[(kq*4+3)*LDT + r] = v.w;
            float4 w = *(const float4*)(W + (size_t)(n0 + r) * K + k0 + (kq << 2));
            Ws[(kq*4+0)*LDT + r] = w.x; Ws[(kq*4+1)*LDT + r] = w.y;
            Ws[(kq*4+2)*LDT + r] = w.z; Ws[(kq*4+3)*LDT + r] = w.w;
        }
        __syncthreads();
        #pragma unroll
        for (int kk = 0; kk < BKT; kk++) {
            float4 a = *(const float4*)(As + kk*LDT + ty*4);
            float4 w = *(const float4*)(Ws + kk*LDT + tx*4);
            acc[0][0] += a.x*w.x; acc[0][1] += a.x*w.y; acc[0][2] += a.x*w.z; acc[0][3] += a.x*w.w;
            acc[1][0] += a.y*w.x; acc[1][1] += a.y*w.y; acc[1][2] += a.y*w.z; acc[1][3] += a.y*w.w;
            acc[2][0] += a.z*w.x; acc[2][1] += a.z*w.y; acc[2][2] += a.z*w.z; acc[2][3] += a.z*w.w;
            acc[3][0] += a.w*w.x; acc[3][1] += a.w*w.y; acc[3][2] += a.w*w.z; acc[3][3] += a.w*w.w;
        }
        __syncthreads();
    }
    #pragma unroll
    for (int i = 0; i < 4; i++) {
        int mr = m0 + ty*4 + i;
        #pragma unroll
        for (int j = 0; j < 4; j++) {
            int n = n0 + tx*4 + j;
            float v = acc[i][j];
            if (bias) v += bias[n];
            Co[(size_t)mr * N + n] = v * out_scale;
        }
    }
}

// ---------- self-attention over the 12-layer axis, one block per batch ----------
__global__ __launch_bounds__(256)
void attn_kernel(const float* __restrict__ qkv, float* __restrict__ ao)
{
    __shared__ float lq[L_IMG * DIM];
    __shared__ float lk[L_IMG * DIM];
    __shared__ float sc[L_IMG * L_IMG];
    __shared__ float sa[L_IMG * L_IMG];
    const int b = blockIdx.x, tid = threadIdx.x;
    for (int i = 0; i < 6; i++) {
        int slot = tid + (i << 8);
        int l = slot >> 7, e4 = slot & 127;
        const float* row = qkv + (size_t)(l * BATCH + b) * 1536;
        *(float4*)(lq + l*DIM + e4*4) = *(const float4*)(row + e4*4);
        *(float4*)(lk + l*DIM + e4*4) = *(const float4*)(row + DIM + e4*4);
    }
    __syncthreads();
    if (tid < 144) {
        int l = tid / 12, m = tid % 12;
        float a = 0.f;
        for (int d4 = 0; d4 < 128; d4++) {
            float4 q = *(const float4*)(lq + l*DIM + d4*4);
            float4 k = *(const float4*)(lk + m*DIM + d4*4);
            a += q.x*k.x + q.y*k.y + q.z*k.z + q.w*k.w;
        }
        sc[tid] = a * SCALEF;
    }
    __syncthreads();
    if (tid < 12) {
        float mx = -1e30f;
        for (int m = 0; m < 12; m++) mx = fmaxf(mx, sc[tid*12 + m]);
        float e[12], s = 0.f;
        for (int m = 0; m < 12; m++) { e[m] = __expf(sc[tid*12 + m] - mx); s += e[m]; }
        float inv = 1.f / s;
        for (int m = 0; m < 12; m++) sa[tid*12 + m] = e[m] * inv;
    }
    __syncthreads();
    for (int i = 0; i < 2; i++) {
        int e = tid + (i << 8);
        float vv[12];
        #pragma unroll
        for (int m = 0; m < 12; m++)
            vv[m] = qkv[(size_t)(m * BATCH + b) * 1536 + 1024 + e];
        #pragma unroll
        for (int l = 0; l < 12; l++) {
            float a = 0.f;
            #pragma unroll
            for (int m = 0; m < 12; m++) a += sa[l*12 + m] * vv[m];
            ao[(size_t)(l * BATCH + b) * DIM + e] = a;
        }
    }
}

// ---------- normalize image features (xs layer 11) ----------
__global__ __launch_bounds__(256)
void img_kernel(const float* __restrict__ xs, float* __restrict__ imgn)
{
    __shared__ float red[256];
    const int b = blockIdx.x, tid = threadIdx.x;
    const float* row = xs + (size_t)(11 * BATCH + b) * DIM;
    float v0 = row[tid], v1 = row[tid + 256];
    red[tid] = v0*v0 + v1*v1;
    __syncthreads();
    for (int s = 128; s > 0; s >>= 1) {
        if (tid < s) red[tid] += red[tid + s];
        __syncthreads();
    }
    float inv = rsqrtf(red[0]);
    imgn[b*DIM + tid]       = v0 * inv;
    imgn[b*DIM + tid + 256] = v1 * inv;
}

// ---------- q2s fp32 [12,64,512] -> q2pb bf16 [64*16, 512], l>=12 zero ----------
__global__ __launch_bounds__(256)
void build_q2p(const float* __restrict__ q2s, unsigned short* __restrict__ q2pb)
{
    const int l = blockIdx.x, b = blockIdx.y, t = threadIdx.x;
    int d0 = t * 2;
    unsigned int o = 0;
    if (l < 12) {
        float2 v = *(const float2*)(q2s + (size_t)(l * BATCH + b) * DIM + d0);
        o = (unsigned int)f2bf(v.x) | ((unsigned int)f2bf(v.y) << 16);
    }
    ((unsigned int*)q2pb)[(size_t)(b * 16 + l) * 256 + t] = o;
}

// ---------- MFMA GEMM: C[M,N] = A[M,K]@W[N,K]^T + bias ; 128x128 tile, BK=32 ----------
// LDS tiles [row][k] with padded stride 40 shorts (80B): frag ds_read_b128 is 2-way (free).
#define LDAB 40
template<typename OutT>
__global__ __launch_bounds__(256)
void gemm_mfma(const unsigned short* __restrict__ A, const unsigned short* __restrict__ W,
               const float* __restrict__ bias, OutT* __restrict__ Co,
               int M, int N, int K, float scale)
{
    __shared__ __align__(16) unsigned short As[128 * LDAB];
    __shared__ __align__(16) unsigned short Ws[128 * LDAB];
    const int tid = threadIdx.x;
    const int m0 = blockIdx.y << 7, n0 = blockIdx.x << 7;
    const int w = tid >> 6, lane = tid & 63;
    const int mt0 = (w & 1) * 4, nt0 = (w >> 1) * 4;
    const int r16 = lane & 15, kq = lane >> 4;
    f32x4 acc[4][4] = {};

    for (int k0 = 0; k0 < K; k0 += 32) {
        #pragma unroll
        for (int i = 0; i < 2; i++) {
            int slot = tid + (i << 8);
            int r = slot >> 2, q = slot & 3;
            *(uint4*)(As + r*LDAB + q*8) = *(const uint4*)(A + (size_t)(m0 + r) * K + k0 + (q << 3));
            *(uint4*)(Ws + r*LDAB + q*8) = *(const uint4*)(W + (size_t)(n0 + r) * K + k0 + (q << 3));
        }
        __syncthreads();
        bf16x8 af[4], bfr[4];
        #pragma unroll
        for (int i = 0; i < 4; i++) {
            af[i]  = *(const bf16x8*)(As + ((mt0 + i)*16 + r16)*LDAB + (kq << 3));
            bfr[i] = *(const bf16x8*)(Ws + ((nt0 + i)*16 + r16)*LDAB + (kq << 3));
        }
        #pragma unroll
        for (int i = 0; i < 4; i++)
            #pragma unroll
            for (int j = 0; j < 4; j++)
                acc[i][j] = __builtin_amdgcn_mfma_f32_16x16x32_bf16(af[i], bfr[j], acc[i][j], 0, 0, 0);
        __syncthreads();
    }
    const int rbase = (lane >> 4) * 4;
    #pragma unroll
    for (int i = 0; i < 4; i++)
        #pragma unroll
        for (int j = 0; j < 4; j++) {
            int gcol = n0 + (nt0 + j) * 16 + r16;
            float bv = bias ? bias[gcol] : 0.f;
            #pragma unroll
            for (int r = 0; r < 4; r++) {
                int grow = m0 + (mt0 + i) * 16 + rbase + r;
                storeo(Co + (size_t)grow * N + gcol, acc[i][j][r] * scale + bv);
            }
        }
}

// ---------- fused scores + softmax(m) + sum_l: one block = (class c, 8 batches) ----------
// Q tile 128 rows (8 b * 16, l>=12 zero-padded), K tile = all 96 text rows of class c.
__global__ __launch_bounds__(256)
void fused_scores(const unsigned short* __restrict__ q2pb, const unsigned short* __restrict__ k2,
                  float* __restrict__ wout)
{
    __shared__ __align__(16) unsigned short As[128 * LDAB];  // 10240 B
    __shared__ __align__(16) unsigned short Ks[96 * LDAB];   // 7680 B
    __shared__ float sS[128 * 100];                          // 51200 B
    __shared__ float wl[8 * NTM];                            // 3072 B
    const int c = blockIdx.x, bg = blockIdx.y, tid = threadIdx.x;
    const int m0 = bg << 7;
    const int w = tid >> 6, lane = tid & 63;
    const int mt0 = w * 2;
    const int r16 = lane & 15, kq = lane >> 4;
    const size_t kb = (size_t)c * NTM * DIM;
    f32x4 acc[2][6] = {};

    for (int k0 = 0; k0 < DIM; k0 += 32) {
        #pragma unroll
        for (int i = 0; i < 2; i++) {
            int slot = tid + (i << 8);
            int r = slot >> 2, q = slot & 3;
            *(uint4*)(As + r*LDAB + q*8) =
                *(const uint4*)(q2pb + (size_t)(m0 + r) * DIM + k0 + (q << 3));
        }
        {
            int r = tid >> 2, q = tid & 3;
            *(uint4*)(Ks + r*LDAB + q*8) =
                *(const uint4*)(k2 + kb + (size_t)r * DIM + k0 + (q << 3));
            if (tid < 128) {
                int slot = tid + 256, r2 = slot >> 2, q2 = slot & 3;
                *(uint4*)(Ks + r2*LDAB + q2*8) =
                    *(const uint4*)(k2 + kb + (size_t)r2 * DIM + k0 + (q2 << 3));
            }
        }
        __syncthreads();
        bf16x8 af[2], bfr[6];
        #pragma unroll
        for (int i = 0; i < 2; i++)
            af[i] = *(const bf16x8*)(As + ((mt0 + i)*16 + r16)*LDAB + (kq << 3));
        #pragma unroll
        for (int j = 0; j < 6; j++)
            bfr[j] = *(const bf16x8*)(Ks + (j*16 + r16)*LDAB + (kq << 3));
        #pragma unroll
        for (int i = 0; i < 2; i++)
            #pragma unroll
            for (int j = 0; j < 6; j++)
                acc[i][j] = __builtin_amdgcn_mfma_f32_16x16x32_bf16(af[i], bfr[j], acc[i][j], 0, 0, 0);
        __syncthreads();
    }

    // scores -> LDS (C/D layout: row=(lane>>4)*4+r, col=lane&15)
    const int rbase = (lane >> 4) * 4;
    #pragma unroll
    for (int i = 0; i < 2; i++)
        #pragma unroll
        for (int j = 0; j < 6; j++)
            #pragma unroll
            for (int r = 0; r < 4; r++)
                sS[((mt0 + i)*16 + rbase + r) * 100 + j*16 + r16] = acc[i][j][r];
    for (int idx = tid; idx < 8 * NTM; idx += 256) wl[idx] = 0.f;
    __syncthreads();

    // softmax over m (cols m*8+t) per (b,l,t); accumulate sum_l/96 into wl
    {
        const int bl = tid >> 5, tt = (tid >> 2) & 7, lh = tid & 3;
        #pragma unroll
        for (int li = 0; li < 3; li++) {
            int l = lh + li * 4;
            const float* row = sS + (bl * 16 + l) * 100 + tt;
            float mx = -1e30f;
            #pragma unroll
            for (int m = 0; m < 12; m++) mx = fmaxf(mx, row[m << 3]);
            float e[12], s = 0.f;
            #pragma unroll
            for (int m = 0; m < 12; m++) { e[m] = __expf(row[m << 3] - mx); s += e[m]; }
            float inv = (1.f / 96.f) / s;
            #pragma unroll
            for (int m = 0; m < 12; m++)
                atomicAdd(&wl[bl * NTM + (m << 3) + tt], e[m] * inv);
        }
    }
    __syncthreads();
    for (int idx = tid; idx < 8 * NTM; idx += 256) {
        int bl = idx / NTM, tm = idx - bl * NTM;
        wout[((size_t)((bg * 8 + bl) * NCLS + c)) * NTM + tm] = wl[idx];
    }
}

// ---------- txt[b,c,:] = sum_tm w[b,c,tm] * v2p[c,tm,:] + cob ; block=(c, 16 batches) ----------
__global__ __launch_bounds__(256)
void txt_kernel(const float* __restrict__ wbuf, const unsigned short* __restrict__ v2p,
                const float* __restrict__ cob, unsigned short* __restrict__ txt)
{
    __shared__ float ws[16 * NTM];
    const int c = blockIdx.x, bg = blockIdx.y, tid = threadIdx.x;
    for (int idx = tid; idx < 16 * NTM; idx += 256) {
        int bl = idx / NTM, tm = idx - bl * NTM;
        ws[idx] = wbuf[((size_t)((bg * 16 + bl) * NCLS + c)) * NTM + tm];
    }
    __syncthreads();
    float a0[16] = {}, a1[16] = {};
    const unsigned int* vrow = (const unsigned int*)(v2p + (size_t)c * NTM * DIM) + tid;
    for (int tm = 0; tm < NTM; tm++) {
        unsigned int u = vrow[tm * 256];
        float vx = __uint_as_float(u << 16);
        float vy = __uint_as_float(u & 0xFFFF0000u);
        #pragma unroll
        for (int bl = 0; bl < 16; bl++) {
            float wv = ws[bl * NTM + tm];
            a0[bl] += wv * vx; a1[bl] += wv * vy;
        }
    }
    int d0 = tid * 2;
    float c0 = cob[d0], c1 = cob[d0 + 1];
    #pragma unroll
    for (int bl = 0; bl < 16; bl++) {
        int b = bg * 16 + bl;
        unsigned int o = (unsigned int)f2bf(a0[bl] + c0) | ((unsigned int)f2bf(a1[bl] + c1) << 16);
        ((unsigned int*)txt)[(size_t)(b * NCLS + c) * 256 + tid] = o;
    }
}

// ---------- n2[b,d] = sum_c txt[b,c,d]^2 ----------
__global__ __launch_bounds__(256)
void n2_kernel(const unsigned short* __restrict__ txt, float* __restrict__ n2)
{
    const int b = blockIdx.x, cg = blockIdx.y, t = threadIdx.x;
    float a0 = 0.f, a1 = 0.f;
    const unsigned int* p = (const unsigned int*)txt + ((size_t)(b * NCLS + cg * 250)) * 256 + t;
    for (int c = 0; c < 250; c++) {
        unsigned int u = p[c * 256];
        float vx = __uint_as_float(u << 16);
        float vy = __uint_as_float(u & 0xFFFF0000u);
        a0 += vx * vx; a1 += vy * vy;
    }
    atomicAdd(&n2[b * DIM + t * 2], a0);
    atomicAdd(&n2[b * DIM + t * 2 + 1], a1);
}

// ---------- u[b,d] = exp(ls) * img_n[b,d] / sqrt(n2[b,d]) ----------
__global__ __launch_bounds__(256)
void u_kernel(const float* __restrict__ imgn, const float* __restrict__ n2,
              const float* __restrict__ logit_scale, float* __restrict__ u)
{
    int i = blockIdx.x * 256 + threadIdx.x;
    float els = expf(logit_scale[0]);
    u[i] = els * imgn[i] * rsqrtf(n2[i]);
}

// ---------- logits[b,c] = sum_d u[b,d] * txt[b,c,d] ----------
__global__ __launch_bounds__(256)
void logits_kernel(const unsigned short* __restrict__ txt, const float* __restrict__ u,
                   float* __restrict__ out)
{
    __shared__ float lu[DIM];
    const int b = blockIdx.y, cg = blockIdx.x, tid = threadIdx.x;
    lu[tid]       = u[b*DIM + tid];
    lu[tid + 256] = u[b*DIM + tid + 256];
    __syncthreads();
    int wave = tid >> 6, lane = tid & 63;
    int c = (cg << 2) + wave;
    const unsigned short* row = txt + (size_t)(b * NCLS + c) * DIM;
    ushort4 p0 = ((const ushort4*)row)[lane*2];
    ushort4 p1 = ((const ushort4*)row)[lane*2 + 1];
    int d0 = lane * 8;
    float s = bf2f(p0.x)*lu[d0]   + bf2f(p0.y)*lu[d0+1] + bf2f(p0.z)*lu[d0+2] + bf2f(p0.w)*lu[d0+3]
            + bf2f(p1.x)*lu[d0+4] + bf2f(p1.y)*lu[d0+5] + bf2f(p1.z)*lu[d0+6] + bf2f(p1.w)*lu[d0+7];
    #pragma unroll
    for (int off = 32; off > 0; off >>= 1) s += __shfl_down(s, off, 64);
    if (lane == 0) out[b*NCLS + c] = s;
}

extern "C" void kernel_launch(void* const* d_in, const int* in_sizes, int n_in,
                              void* d_out, int out_size, void* d_ws, size_t ws_size,
                              hipStream_t stream)
{
    const float* x   = (const float*)d_in[0];
    const float* tfe = (const float*)d_in[1];
    const float* siw = (const float*)d_in[2];
    const float* sib = (const float*)d_in[3];
    const float* sow = (const float*)d_in[4];
    const float* sob = (const float*)d_in[5];
    const float* ciw = (const float*)d_in[6];
    const float* cib = (const float*)d_in[7];
    const float* cow = (const float*)d_in[8];
    const float* cob = (const float*)d_in[9];
    const float* ls  = (const float*)d_in[10];
    float* out = (float*)d_out;

    char* p = (char*)d_ws;
    auto alloc = [&](size_t bytes) { char* r = p; p += (bytes + 255) & ~255ull; return r; };
    unsigned short* tfeb = (unsigned short*)alloc((size_t)49152000 * 2);   // 98.3 MB
    unsigned short* k2   = (unsigned short*)alloc((size_t)96000 * DIM * 2);
    unsigned short* v2p  = (unsigned short*)alloc((size_t)96000 * DIM * 2);
    float* wbuf          = (float*)alloc((size_t)BATCH * NCLS * NTM * 4);  // 24.6 MB
    float* qkv           = (float*)alloc((size_t)768 * 1536 * 4);
    float* ao            = (float*)alloc((size_t)768 * DIM * 4);
    float* xs            = (float*)alloc((size_t)768 * DIM * 4);
    float* q2s           = (float*)alloc((size_t)768 * DIM * 4);
    unsigned short* q2pb = (unsigned short*)alloc((size_t)1024 * DIM * 2);
    unsigned short* cWkb = (unsigned short*)alloc((size_t)DIM * DIM * 2);
    unsigned short* Wvob = (unsigned short*)alloc((size_t)DIM * DIM * 2);
    float* bvo           = (float*)alloc(DIM * 4);
    float* n2            = (float*)alloc(BATCH * DIM * 4);
    float* uu            = (float*)alloc(BATCH * DIM * 4);
    float* imgn          = (float*)alloc(BATCH * DIM * 4);
    unsigned short* txt  = tfeb;   // alias: tfeb dead after v2p GEMM, txt written after

    hipMemsetAsync(n2, 0, BATCH * DIM * 4, stream);

    // weight/text prep
    f2bf_kernel<<<48000, 256, 0, stream>>>(tfe, tfeb, 49152000);
    f2bf_kernel<<<256, 256, 0, stream>>>(ciw + 512*512, cWkb, 262144);
    fold_wvo<<<512, 256, 0, stream>>>(cow, ciw + 1024*512, cib + 1024, Wvob, bvo);

    // self-attn head (fp32, small)
    gemm_bt_f32<<<dim3(24, 12), 256, 0, stream>>>(x, siw, sib, qkv, 768, 1536, 512, 1.f);
    attn_kernel<<<64, 256, 0, stream>>>(qkv, ao);
    gemm_bt_f32<<<dim3(8, 12), 256, 0, stream>>>(ao, sow, sob, xs, 768, 512, 512, 1.f);
    img_kernel<<<64, 256, 0, stream>>>(xs, imgn);
    gemm_bt_f32<<<dim3(8, 12), 256, 0, stream>>>(xs, ciw, cib, q2s, 768, 512, 512, SCALEF);
    build_q2p<<<dim3(16, 64), 256, 0, stream>>>(q2s, q2pb);

    // k2 / v2' projections (MFMA)
    gemm_mfma<unsigned short><<<dim3(4, 750), 256, 0, stream>>>(
        tfeb, cWkb, cib + 512, k2, 96000, 512, 512, 1.f);
    gemm_mfma<unsigned short><<<dim3(4, 750), 256, 0, stream>>>(
        tfeb, Wvob, bvo, v2p, 96000, 512, 512, 1.f);

    // fused scores+softmax -> w[b,c,96]
    fused_scores<<<dim3(1000, 8), 256, 0, stream>>>(q2pb, k2, wbuf);

    // txt = w @ v2' + cob  (bf16), then norms and logits
    txt_kernel<<<dim3(1000, 4), 256, 0, stream>>>(wbuf, v2p, cob, txt);
    n2_kernel<<<dim3(64, 4), 256, 0, stream>>>(txt, n2);
    u_kernel<<<128, 256, 0, stream>>>(imgn, n2, ls, uu);
    logits_kernel<<<dim3(250, 64), 256, 0, stream>>>(txt, uu, out);
}